// Round 1
// baseline (449.168 us; speedup 1.0000x reference)
//
#include <hip/hip_runtime.h>

#define V_   3
#define N_   200000
#define D_   128
#define B_   32768
#define K_   10
#define TOT_ 65536

constexpr int BLOCKS_PER_TERM = 512;
constexpr int ROWS_PER_BLOCK  = B_ / BLOCKS_PER_TERM;          // 64
constexpr int WAVES_PER_BLOCK = 4;                             // 256 threads
constexpr int ROWS_PER_WAVE   = ROWS_PER_BLOCK / WAVES_PER_BLOCK; // 16

__device__ __forceinline__ float wave_sum(float v) {
#pragma unroll
    for (int o = 32; o > 0; o >>= 1) v += __shfl_xor(v, o, 64);
    return v;
}

__device__ __forceinline__ float log_sigmoid(float x) {
    // -log(1+exp(-x)) = min(x,0) - log1p(exp(-|x|))
    float ax = fabsf(x);
    return fminf(x, 0.f) - __logf(1.f + __expf(-ax));
}

__global__ __launch_bounds__(256) void sgns_kernel(
    const int*   __restrict__ countp,
    const int*   __restrict__ shuffle,
    const int*   __restrict__ nodes_idx,
    const int*   __restrict__ neigh_idx,
    const int*   __restrict__ neg1,
    const int*   __restrict__ neg2,
    const int*   __restrict__ neg3,
    const float* __restrict__ node_W,
    const float* __restrict__ neigh_W,
    float*       __restrict__ acc)   // acc[0]=cost1 sum, acc[1]=cost2 sum, acc[2]=cost3 sum
{
    const int t    = blockIdx.x / BLOCKS_PER_TERM;   // term id 0..14
    const int blk  = blockIdx.x % BLOCKS_PER_TERM;
    const int wave = threadIdx.x >> 6;
    const int lane = threadIdx.x & 63;
    const int count = countp[0];

    int i, j, type;
    if (t < 3)      { type = 0; i = t;         j = t; }
    else if (t < 9) { type = 1; int p = t - 3; j = p >> 1; int q = p & 1; i = (q < j) ? q : q + 1; }
    else            { type = 2; int p = t - 9; j = p >> 1; int q = p & 1; i = (q < j) ? q : q + 1; }

    const int*   negBase;
    const float* negTable;
    if (type == 0)      { negTable = neigh_W + (size_t)i * N_ * D_; negBase = neg1 + (size_t)i * B_ * K_; }
    else if (type == 1) { negTable = node_W  + (size_t)j * N_ * D_; negBase = neg2 + (size_t)(j * V_ + i) * B_ * K_; }
    else                { negTable = neigh_W + (size_t)j * N_ * D_; negBase = neg3 + (size_t)(j * V_ + i) * B_ * K_; }

    float wsum = 0.f;
    const int rowbase = blk * ROWS_PER_BLOCK + wave * ROWS_PER_WAVE;

    for (int r = 0; r < ROWS_PER_WAVE; ++r) {
        const int b  = rowbase + r;
        const int sh = shuffle[i * TOT_ + count + b];
        const int ns = nodes_idx[i * TOT_ + sh];

        const float2* crow = (const float2*)(node_W + ((size_t)i * N_ + ns) * (size_t)D_);
        float2 c = crow[lane];

        const float2* xrow;
        if (type == 0) {
            int gs = neigh_idx[i * TOT_ + sh];
            xrow = (const float2*)(neigh_W + ((size_t)i * N_ + gs) * (size_t)D_);
        } else if (type == 1) {
            xrow = (const float2*)(node_W + ((size_t)j * N_ + ns) * (size_t)D_);
        } else {
            int gs = neigh_idx[i * TOT_ + sh];
            xrow = (const float2*)(neigh_W + ((size_t)j * N_ + gs) * (size_t)D_);
        }
        float2 x = xrow[lane];

        // lanes 0..9 load the 10 contiguous neg indices, broadcast via shfl
        int myidx = (lane < K_) ? negBase[(size_t)b * K_ + lane] : 0;

        float pos_p = c.x * x.x + c.y * x.y;

        float negp[K_];
#pragma unroll
        for (int k = 0; k < K_; ++k) {
            int nk = __shfl(myidx, k, 64);
            const float2* nrow = (const float2*)(negTable + (size_t)nk * (size_t)D_);
            float2 nv = nrow[lane];
            negp[k] = c.x * nv.x + c.y * nv.y;
        }

        float pos = wave_sum(pos_p);
        float rowacc = log_sigmoid(pos);
#pragma unroll
        for (int k = 0; k < K_; ++k) {
            float nd = wave_sum(negp[k]);
            rowacc += log_sigmoid(-nd);
        }
        wsum += rowacc;
    }

    __shared__ float part[WAVES_PER_BLOCK];
    if (lane == 0) part[wave] = wsum;
    __syncthreads();
    if (threadIdx.x == 0) {
        float s = part[0] + part[1] + part[2] + part[3];
        atomicAdd(&acc[type], s);
    }
}

__global__ void finalize_kernel(const float* __restrict__ acc,
                                const float* __restrict__ hyp1,
                                const float* __restrict__ hyp2,
                                float* __restrict__ out)
{
    const float invB = 1.0f / (float)B_;
    float s1 = acc[0], s2 = acc[1], s3 = acc[2];
    out[0] = -(s1 * (invB / 9.0f) + hyp1[0] * s2 * (invB / 18.0f) + hyp2[0] * s3 * (invB / 18.0f));
}

extern "C" void kernel_launch(void* const* d_in, const int* in_sizes, int n_in,
                              void* d_out, int out_size, void* d_ws, size_t ws_size,
                              hipStream_t stream)
{
    const int*   countp    = (const int*)d_in[0];
    const int*   shuffle   = (const int*)d_in[1];
    const int*   nodes_idx = (const int*)d_in[2];
    const int*   neigh_idx = (const int*)d_in[3];
    const int*   neg1      = (const int*)d_in[4];
    const int*   neg2      = (const int*)d_in[5];
    const int*   neg3      = (const int*)d_in[6];
    const float* node_W    = (const float*)d_in[7];
    const float* neigh_W   = (const float*)d_in[8];
    const float* hyp1      = (const float*)d_in[9];
    const float* hyp2      = (const float*)d_in[10];

    float* acc = (float*)d_ws;
    hipMemsetAsync(acc, 0, 3 * sizeof(float), stream);

    dim3 grid(15 * BLOCKS_PER_TERM);
    dim3 block(256);
    sgns_kernel<<<grid, block, 0, stream>>>(countp, shuffle, nodes_idx, neigh_idx,
                                            neg1, neg2, neg3, node_W, neigh_W, acc);

    finalize_kernel<<<1, 1, 0, stream>>>(acc, hyp1, hyp2, (float*)d_out);
}

// Round 2
// 428.202 us; speedup vs baseline: 1.0490x; 1.0490x over previous
//
#include <hip/hip_runtime.h>

#define V_   3
#define N_   200000
#define D_   128
#define B_   32768
#define K_   10
#define TOT_ 65536

constexpr int BLOCKS_PER_TERM = 512;
constexpr int ROWS_PER_BLOCK  = B_ / BLOCKS_PER_TERM;             // 64
constexpr int WAVES_PER_BLOCK = 4;                                // 256 threads
constexpr int ROWS_PER_WAVE   = ROWS_PER_BLOCK / WAVES_PER_BLOCK; // 16
constexpr int GROUPS_PER_WAVE = 4;                                // 16 lanes/row
constexpr int ITERS           = ROWS_PER_WAVE / GROUPS_PER_WAVE;  // 4

// Term schedule grouped by negative-sample table slice for L3 locality.
// {type, i, j}: type0 negs from neigh_W[i]; type1 negs from node_W[j];
// type2 negs from neigh_W[j].
__device__ const int TMAP[15][3] = {
    {0, 0, 0}, {2, 1, 0}, {2, 2, 0},   // neigh_W[0]
    {0, 1, 1}, {2, 0, 1}, {2, 2, 1},   // neigh_W[1]
    {0, 2, 2}, {2, 0, 2}, {2, 1, 2},   // neigh_W[2]
    {1, 1, 0}, {1, 2, 0},              // node_W[0]
    {1, 0, 1}, {1, 2, 1},              // node_W[1]
    {1, 0, 2}, {1, 1, 2},              // node_W[2]
};

__device__ __forceinline__ float grp_sum16(float v) {
    v += __shfl_xor(v, 1, 64);
    v += __shfl_xor(v, 2, 64);
    v += __shfl_xor(v, 4, 64);
    v += __shfl_xor(v, 8, 64);
    return v;
}

__device__ __forceinline__ float dot8(float4 a0, float4 a1, float4 b0, float4 b1) {
    float s = a0.x * b0.x;
    s = fmaf(a0.y, b0.y, s);
    s = fmaf(a0.z, b0.z, s);
    s = fmaf(a0.w, b0.w, s);
    s = fmaf(a1.x, b1.x, s);
    s = fmaf(a1.y, b1.y, s);
    s = fmaf(a1.z, b1.z, s);
    s = fmaf(a1.w, b1.w, s);
    return s;
}

__device__ __forceinline__ float log_sigmoid(float x) {
    float ax = fabsf(x);
    return fminf(x, 0.f) - __logf(1.f + __expf(-ax));
}

__global__ __launch_bounds__(256) void sgns_kernel(
    const int*   __restrict__ countp,
    const int*   __restrict__ shuffle,
    const int*   __restrict__ nodes_idx,
    const int*   __restrict__ neigh_idx,
    const int*   __restrict__ neg1,
    const int*   __restrict__ neg2,
    const int*   __restrict__ neg3,
    const float* __restrict__ node_W,
    const float* __restrict__ neigh_W,
    float*       __restrict__ acc)
{
    const int slot = blockIdx.x / BLOCKS_PER_TERM;   // 0..14
    const int blk  = blockIdx.x % BLOCKS_PER_TERM;
    const int wave = threadIdx.x >> 6;
    const int lane = threadIdx.x & 63;
    const int grp  = lane >> 4;       // 0..3, row group within wave
    const int lw   = lane & 15;       // lane within group
    const int count = countp[0];

    const int type = TMAP[slot][0];
    const int i    = TMAP[slot][1];
    const int j    = TMAP[slot][2];

    const int*   negBase;
    const float* negTable;
    if (type == 0)      { negTable = neigh_W + (size_t)i * N_ * D_; negBase = neg1 + (size_t)i * B_ * K_; }
    else if (type == 1) { negTable = node_W  + (size_t)j * N_ * D_; negBase = neg2 + (size_t)(j * V_ + i) * B_ * K_; }
    else                { negTable = neigh_W + (size_t)j * N_ * D_; negBase = neg3 + (size_t)(j * V_ + i) * B_ * K_; }

    float wsum = 0.f;
    const int rowbase = blk * ROWS_PER_BLOCK + wave * ROWS_PER_WAVE;

    for (int r = 0; r < ITERS; ++r) {
        const int b  = rowbase + r * GROUPS_PER_WAVE + grp;
        const int sh = shuffle[i * TOT_ + count + b];        // 16 lanes same addr
        const int ns = nodes_idx[i * TOT_ + sh];

        const float* crow = node_W + ((size_t)i * N_ + ns) * (size_t)D_;
        float4 c0 = *(const float4*)(crow + lw * 4);
        float4 c1 = *(const float4*)(crow + 64 + lw * 4);

        const float* xrow;
        if (type == 0) {
            int gs = neigh_idx[i * TOT_ + sh];
            xrow = neigh_W + ((size_t)i * N_ + gs) * (size_t)D_;
        } else if (type == 1) {
            xrow = node_W + ((size_t)j * N_ + ns) * (size_t)D_;
        } else {
            int gs = neigh_idx[i * TOT_ + sh];
            xrow = neigh_W + ((size_t)j * N_ + gs) * (size_t)D_;
        }
        float4 x0 = *(const float4*)(xrow + lw * 4);
        float4 x1 = *(const float4*)(xrow + 64 + lw * 4);

        int myidx = (lw < K_) ? negBase[(size_t)b * K_ + lw] : 0;

        float pos = grp_sum16(dot8(c0, c1, x0, x1));
        float rowacc = log_sigmoid(pos);

#pragma unroll
        for (int k = 0; k < K_; ++k) {
            int nk = __shfl(myidx, (lane & 48) | k, 64);
            const float* nrow = negTable + (size_t)nk * (size_t)D_;
            float4 n0 = *(const float4*)(nrow + lw * 4);
            float4 n1 = *(const float4*)(nrow + 64 + lw * 4);
            float nd = grp_sum16(dot8(c0, c1, n0, n1));
            rowacc += log_sigmoid(-nd);
        }
        wsum += rowacc;   // identical across the 16 lanes of this group
    }

    // sum across the 4 groups (each group's lanes hold that group's total)
    wsum += __shfl_xor(wsum, 16, 64);
    wsum += __shfl_xor(wsum, 32, 64);

    __shared__ float part[WAVES_PER_BLOCK];
    if (lane == 0) part[wave] = wsum;
    __syncthreads();
    if (threadIdx.x == 0) {
        float s = part[0] + part[1] + part[2] + part[3];
        atomicAdd(&acc[type], s);
    }
}

__global__ void finalize_kernel(const float* __restrict__ acc,
                                const float* __restrict__ hyp1,
                                const float* __restrict__ hyp2,
                                float* __restrict__ out)
{
    const float invB = 1.0f / (float)B_;
    float s1 = acc[0], s2 = acc[1], s3 = acc[2];
    out[0] = -(s1 * (invB / 9.0f) + hyp1[0] * s2 * (invB / 18.0f) + hyp2[0] * s3 * (invB / 18.0f));
}

extern "C" void kernel_launch(void* const* d_in, const int* in_sizes, int n_in,
                              void* d_out, int out_size, void* d_ws, size_t ws_size,
                              hipStream_t stream)
{
    const int*   countp    = (const int*)d_in[0];
    const int*   shuffle   = (const int*)d_in[1];
    const int*   nodes_idx = (const int*)d_in[2];
    const int*   neigh_idx = (const int*)d_in[3];
    const int*   neg1      = (const int*)d_in[4];
    const int*   neg2      = (const int*)d_in[5];
    const int*   neg3      = (const int*)d_in[6];
    const float* node_W    = (const float*)d_in[7];
    const float* neigh_W   = (const float*)d_in[8];
    const float* hyp1      = (const float*)d_in[9];
    const float* hyp2      = (const float*)d_in[10];

    float* acc = (float*)d_ws;
    hipMemsetAsync(acc, 0, 3 * sizeof(float), stream);

    dim3 grid(15 * BLOCKS_PER_TERM);
    dim3 block(256);
    sgns_kernel<<<grid, block, 0, stream>>>(countp, shuffle, nodes_idx, neigh_idx,
                                            neg1, neg2, neg3, node_W, neigh_W, acc);

    finalize_kernel<<<1, 1, 0, stream>>>(acc, hyp1, hyp2, (float*)d_out);
}

// Round 3
// 423.049 us; speedup vs baseline: 1.0617x; 1.0122x over previous
//
#include <hip/hip_runtime.h>

#define V_   3
#define N_   200000
#define D_   128
#define B_   32768
#define K_   10
#define TOT_ 65536

constexpr int BLOCKS_PER_TERM = 512;
constexpr int ROWS_PER_BLOCK  = B_ / BLOCKS_PER_TERM;             // 64
constexpr int WAVES_PER_BLOCK = 4;                                // 256 threads
constexpr int ROWS_PER_WAVE   = ROWS_PER_BLOCK / WAVES_PER_BLOCK; // 16
constexpr int GROUPS_PER_WAVE = 4;                                // 16 lanes/row
constexpr int ITERS           = ROWS_PER_WAVE / GROUPS_PER_WAVE;  // 4

// Term schedule grouped by negative-sample table slice for L3 locality.
__device__ const int TMAP[15][3] = {
    {0, 0, 0}, {2, 1, 0}, {2, 2, 0},   // negs from neigh_W[0]
    {0, 1, 1}, {2, 0, 1}, {2, 2, 1},   // neigh_W[1]
    {0, 2, 2}, {2, 0, 2}, {2, 1, 2},   // neigh_W[2]
    {1, 1, 0}, {1, 2, 0},              // node_W[0]
    {1, 0, 1}, {1, 2, 1},              // node_W[1]
    {1, 0, 2}, {1, 1, 2},              // node_W[2]
};

template <int CTRL>
__device__ __forceinline__ float dpp_add(float v) {
    int x = __builtin_amdgcn_update_dpp(0, __float_as_int(v), CTRL, 0xF, 0xF, true);
    return v + __int_as_float(x);
}

// 16-lane sum entirely on the VALU pipe (no LDS/DS):
//   xor1 = quad_perm[1,0,3,2] (0xB1), xor2 = quad_perm[2,3,0,1] (0x4E),
//   then row_ror:4 (0x124) + row_ror:8 (0x128) fold the 4 quad-sums.
__device__ __forceinline__ float grp_sum16(float v) {
    v = dpp_add<0xB1>(v);
    v = dpp_add<0x4E>(v);
    v = dpp_add<0x124>(v);
    v = dpp_add<0x128>(v);
    return v;
}

__device__ __forceinline__ float dot8(float4 a0, float4 a1, float4 b0, float4 b1) {
    float s = a0.x * b0.x;
    s = fmaf(a0.y, b0.y, s);
    s = fmaf(a0.z, b0.z, s);
    s = fmaf(a0.w, b0.w, s);
    s = fmaf(a1.x, b1.x, s);
    s = fmaf(a1.y, b1.y, s);
    s = fmaf(a1.z, b1.z, s);
    s = fmaf(a1.w, b1.w, s);
    return s;
}

__device__ __forceinline__ float log_sigmoid(float x) {
    float ax = fabsf(x);
    return fminf(x, 0.f) - __logf(1.f + __expf(-ax));
}

__global__ __launch_bounds__(256) void sgns_kernel(
    const int*   __restrict__ countp,
    const int*   __restrict__ shuffle,
    const int*   __restrict__ nodes_idx,
    const int*   __restrict__ neigh_idx,
    const int*   __restrict__ neg1,
    const int*   __restrict__ neg2,
    const int*   __restrict__ neg3,
    const float* __restrict__ node_W,
    const float* __restrict__ neigh_W,
    float*       __restrict__ acc)
{
    const int slot = blockIdx.x / BLOCKS_PER_TERM;
    const int blk  = blockIdx.x % BLOCKS_PER_TERM;
    const int wave = threadIdx.x >> 6;
    const int lane = threadIdx.x & 63;
    const int grp  = lane >> 4;
    const int lw   = lane & 15;
    const int count = countp[0];

    const int type = TMAP[slot][0];
    const int i    = TMAP[slot][1];
    const int j    = TMAP[slot][2];

    const int*   negBase;
    const float* negTable;
    if (type == 0)      { negTable = neigh_W + (size_t)i * N_ * D_; negBase = neg1 + (size_t)i * B_ * K_; }
    else if (type == 1) { negTable = node_W  + (size_t)j * N_ * D_; negBase = neg2 + (size_t)(j * V_ + i) * B_ * K_; }
    else                { negTable = neigh_W + (size_t)j * N_ * D_; negBase = neg3 + (size_t)(j * V_ + i) * B_ * K_; }

    float wsum = 0.f;
    const int rowbase = blk * ROWS_PER_BLOCK + wave * ROWS_PER_WAVE;

    for (int r = 0; r < ITERS; ++r) {
        const int b  = rowbase + r * GROUPS_PER_WAVE + grp;
        const int sh = shuffle[i * TOT_ + count + b];
        const int ns = nodes_idx[i * TOT_ + sh];

        const float* crow = node_W + ((size_t)i * N_ + ns) * (size_t)D_;
        float4 c0 = *(const float4*)(crow + lw * 4);
        float4 c1 = *(const float4*)(crow + 64 + lw * 4);

        const float* xrow;
        if (type == 0) {
            int gs = neigh_idx[i * TOT_ + sh];
            xrow = neigh_W + ((size_t)i * N_ + gs) * (size_t)D_;
        } else if (type == 1) {
            xrow = node_W + ((size_t)j * N_ + ns) * (size_t)D_;
        } else {
            int gs = neigh_idx[i * TOT_ + sh];
            xrow = neigh_W + ((size_t)j * N_ + gs) * (size_t)D_;
        }
        float4 x0 = *(const float4*)(xrow + lw * 4);
        float4 x1 = *(const float4*)(xrow + 64 + lw * 4);

        int myidx = (lw < K_) ? negBase[(size_t)b * K_ + lw] : 0;

        // Broadcast the 10 neg indices for this group's row.
        int nks[K_];
#pragma unroll
        for (int k = 0; k < K_; ++k)
            nks[k] = __shfl(myidx, (lane & 48) | k, 64);

        // Issue ALL 20 row loads before any reduction (MLP).
        float4 n0[K_], n1[K_];
#pragma unroll
        for (int k = 0; k < K_; ++k) {
            const float* nrow = negTable + (size_t)nks[k] * (size_t)D_;
            n0[k] = *(const float4*)(nrow + lw * 4);
            n1[k] = *(const float4*)(nrow + 64 + lw * 4);
        }

        float rowacc = log_sigmoid(grp_sum16(dot8(c0, c1, x0, x1)));
#pragma unroll
        for (int k = 0; k < K_; ++k) {
            float nd = grp_sum16(dot8(c0, c1, n0[k], n1[k]));
            rowacc += log_sigmoid(-nd);
        }
        wsum += rowacc;   // identical across the 16 lanes of this group
    }

    // fold the 4 groups
    wsum += __shfl_xor(wsum, 16, 64);
    wsum += __shfl_xor(wsum, 32, 64);

    __shared__ float part[WAVES_PER_BLOCK];
    if (lane == 0) part[wave] = wsum;
    __syncthreads();
    if (threadIdx.x == 0) {
        float s = part[0] + part[1] + part[2] + part[3];
        atomicAdd(&acc[type], s);
    }
}

__global__ void finalize_kernel(const float* __restrict__ acc,
                                const float* __restrict__ hyp1,
                                const float* __restrict__ hyp2,
                                float* __restrict__ out)
{
    const float invB = 1.0f / (float)B_;
    float s1 = acc[0], s2 = acc[1], s3 = acc[2];
    out[0] = -(s1 * (invB / 9.0f) + hyp1[0] * s2 * (invB / 18.0f) + hyp2[0] * s3 * (invB / 18.0f));
}

extern "C" void kernel_launch(void* const* d_in, const int* in_sizes, int n_in,
                              void* d_out, int out_size, void* d_ws, size_t ws_size,
                              hipStream_t stream)
{
    const int*   countp    = (const int*)d_in[0];
    const int*   shuffle   = (const int*)d_in[1];
    const int*   nodes_idx = (const int*)d_in[2];
    const int*   neigh_idx = (const int*)d_in[3];
    const int*   neg1      = (const int*)d_in[4];
    const int*   neg2      = (const int*)d_in[5];
    const int*   neg3      = (const int*)d_in[6];
    const float* node_W    = (const float*)d_in[7];
    const float* neigh_W   = (const float*)d_in[8];
    const float* hyp1      = (const float*)d_in[9];
    const float* hyp2      = (const float*)d_in[10];

    float* acc = (float*)d_ws;
    hipMemsetAsync(acc, 0, 3 * sizeof(float), stream);

    dim3 grid(15 * BLOCKS_PER_TERM);
    dim3 block(256);
    sgns_kernel<<<grid, block, 0, stream>>>(countp, shuffle, nodes_idx, neigh_idx,
                                            neg1, neg2, neg3, node_W, neigh_W, acc);

    finalize_kernel<<<1, 1, 0, stream>>>(acc, hyp1, hyp2, (float*)d_out);
}